// Round 4
// baseline (339.265 us; speedup 1.0000x reference)
//
#include <hip/hip_runtime.h>

#define B 64
#define N 1024
#define E 16384
#define WPR 32          // words per adjacency row = N/32
#define NITER 5

// ---- workspace layout (bytes) ----
// [ Kmax 256B | feats 256KiB ] <- zeroed by memset
// [ adj 8MiB | keys 256KiB | cnt 256KiB | gram 16KiB ] <- fully overwritten
#define K_OFF     0
#define FEATS_OFF 256
#define FEATS_BYTES ((size_t)B * N * 4)
#define ZERO_BYTES (FEATS_OFF + FEATS_BYTES)
#define ADJ_OFF   ZERO_BYTES
#define ADJ_BYTES ((size_t)B * N * WPR * 4)
#define KEYS_OFF  (ADJ_OFF + ADJ_BYTES)
#define KEYS_BYTES ((size_t)B * N * 4)
#define CNT_OFF   (KEYS_OFF + KEYS_BYTES)
#define CNT_BYTES ((size_t)B * N * 4)
#define GRAM_OFF  (CNT_OFF + CNT_BYTES)

// Bit adjacency via global atomicOr (R2-measured 42us; R3's LDS-tiled variant
// was SLOWER: 4x redundant edge reads + 1 block/CU latency exposure).
__global__ void build_adj_k(const int* __restrict__ src, const int* __restrict__ dst,
                            unsigned int* __restrict__ adj) {
    int idx = blockIdx.x * blockDim.x + threadIdx.x;
    if (idx >= B * E) return;
    int b = idx >> 14;
    int s = src[idx];
    int d = dst[idx];
    atomicOr(&adj[((size_t)(b * N + s)) * WPR + (d >> 5)], 1u << (d & 31));
}

// Kmax[b] = max_i popcount(row). Block reduce -> 4 atomics/graph.
__global__ void kmax_k(const unsigned int* __restrict__ adj, int* __restrict__ Kmax) {
    __shared__ int red[256];
    int t = threadIdx.x;
    int idx = blockIdx.x * 256 + t;
    const uint4* row = (const uint4*)(adj + (size_t)idx * WPR);
    int d = 0;
#pragma unroll
    for (int w = 0; w < WPR / 4; ++w) {
        uint4 v = row[w];
        d += __popc(v.x) + __popc(v.y) + __popc(v.z) + __popc(v.w);
    }
    red[t] = d;
    __syncthreads();
#pragma unroll
    for (int off = 128; off > 0; off >>= 1) {
        if (t < off) red[t] = max(red[t], red[t + off]);
        __syncthreads();
    }
    if (t == 0) atomicMax(&Kmax[blockIdx.x >> 2], red[0]);
}

// Shared device helper: gather deg/seg from bit row + exact-_rn hash -> monotone uint key.
__device__ __forceinline__ unsigned int hash_key(const unsigned int* row, const int* s_lab,
                                                 int my_lab, float Kf, float w0, float w1) {
    int s = 0, d = 0;
#pragma unroll 4
    for (int w = 0; w < WPR; ++w) {
        unsigned int word = row[w];
        d += __popc(word);
        int base = w << 5;
        while (word) {
            int j = __ffs(word) - 1;
            word &= word - 1;
            s += s_lab[base + j];
        }
    }
    float t1 = __fmul_rn(__fmul_rn(Kf, w0), (float)my_lab);
    float t2 = __fmul_rn(w1, __fsub_rn(__fadd_rn((float)s, (float)d), Kf));
    float h  = __fadd_rn(t1, t2);
    unsigned int bits = __float_as_uint(h);
    if (bits == 0x80000000u) bits = 0u;                       // -0 == +0
    return (bits & 0x80000000u) ? ~bits : (bits | 0x80000000u);
}

// init: bincount initial labels (<16) + first hash -> keys. One block/graph.
__global__ void __launch_bounds__(1024) init_hash_k(const unsigned int* __restrict__ adj,
                                                    const int* __restrict__ Kmax,
                                                    const float* __restrict__ hw,
                                                    const int* __restrict__ lab0,
                                                    unsigned int* __restrict__ feats,
                                                    unsigned int* __restrict__ keys) {
    __shared__ int s_lab[N];
    __shared__ unsigned int cnt16[16];
    int b = blockIdx.x, t = threadIdx.x;
    int l = lab0[(size_t)b * N + t];
    s_lab[t] = l;
    if (t < 16) cnt16[t] = 0;
    __syncthreads();
    atomicAdd(&cnt16[l], 1u);
    __syncthreads();
    if (t < 16) feats[(size_t)b * N + t] = cnt16[t];          // feats pre-zeroed
    keys[(size_t)b * N + t] = hash_key(adj + ((size_t)b * N + t) * WPR, s_lab, l,
                                       (float)Kmax[b], hw[0], hw[1]);
}

// c_i = #{j : key_j < key_i}. 4 blocks/graph -> all 256 CUs busy; each block
// stages the graph's 4KB keys and counts for 256 nodes (256 b128 LDS broadcasts).
__global__ void __launch_bounds__(256) count_k(const unsigned int* __restrict__ keys,
                                               int* __restrict__ cnt) {
    __shared__ unsigned int s_key[N];
    int t = threadIdx.x;
    int b = blockIdx.x >> 2;
    int part = blockIdx.x & 3;
    const unsigned int* kg = keys + (size_t)b * N;
#pragma unroll
    for (int k = 0; k < 4; ++k) s_key[t + k * 256] = kg[t + k * 256];
    __syncthreads();
    unsigned int ikey = s_key[part * 256 + t];
    int c = 0;
    const uint4* k4 = (const uint4*)s_key;
#pragma unroll 8
    for (int j = 0; j < N / 4; ++j) {
        uint4 v = k4[j];
        c += (v.x < ikey) + (v.y < ikey) + (v.z < ikey) + (v.w < ikey);
    }
    cnt[(size_t)b * N + part * 256 + t] = c;
}

// rank from counts (distinct class <-> distinct start offset c: flag+scan),
// bincount into feats, then (fused) next-iteration hash -> keys.
__global__ void __launch_bounds__(1024) rankhash_k(const unsigned int* __restrict__ adj,
                                                   const int* __restrict__ Kmax,
                                                   const float* __restrict__ hw,
                                                   const int* __restrict__ cnt,
                                                   unsigned int* __restrict__ feats,
                                                   unsigned int* __restrict__ keys,
                                                   int do_hash) {
    __shared__ int s_a[N];              // flags -> later rank counts
    __shared__ int s_scan[N];
    __shared__ int s_lab[N];
    __shared__ int s_wsum[16];
    int b = blockIdx.x, t = threadIdx.x;
    int lane = t & 63, w = t >> 6;
    int c = cnt[(size_t)b * N + t];
    s_a[t] = 0;
    __syncthreads();
    s_a[c] = 1;                         // same class -> same c (benign race)
    __syncthreads();
    // inclusive scan of flags: shfl intra-wave + serial wave-sum prefix
    int f = s_a[t];
#pragma unroll
    for (int d = 1; d < 64; d <<= 1) {
        int v = __shfl_up(f, d);
        if (lane >= d) f += v;
    }
    if (lane == 63) s_wsum[w] = f;
    __syncthreads();
    if (t == 0) {
        int run = 0;
#pragma unroll
        for (int k = 0; k < 16; ++k) { int tmp = s_wsum[k]; s_wsum[k] = run; run += tmp; }
    }
    __syncthreads();
    s_scan[t] = f + s_wsum[w];
    __syncthreads();
    int rank = s_scan[c] - 1;
    s_lab[t] = rank;
    // bincount ranks -> feats (row b owned by this block)
    s_a[t] = 0;
    __syncthreads();
    atomicAdd((unsigned int*)&s_a[rank], 1u);
    __syncthreads();
    unsigned int add = (unsigned int)s_a[t];
    if (add) feats[(size_t)b * N + t] += add;
    if (do_hash) {
        keys[(size_t)b * N + t] = hash_key(adj + ((size_t)b * N + t) * WPR, s_lab, rank,
                                           (float)Kmax[b], hw[0], hw[1]);
    }
}

// gram[i,j] = dot(feats[i], feats[j]) — exact in int32
__global__ void gram_k(const unsigned int* __restrict__ feats, float* __restrict__ gram) {
    int i = blockIdx.x, j = blockIdx.y;
    int lane = threadIdx.x;
    const unsigned int* fi = feats + (size_t)i * N;
    const unsigned int* fj = feats + (size_t)j * N;
    int s = 0;
    for (int l = lane; l < N; l += 64) s += (int)(fi[l] * fj[l]);
#pragma unroll
    for (int off = 32; off > 0; off >>= 1) s += __shfl_down(s, off);
    if (lane == 0) gram[i * B + j] = (float)s;
}

__global__ void norm_k(const float* __restrict__ gram, float* __restrict__ out) {
    int idx = blockIdx.x * blockDim.x + threadIdx.x;
    if (idx >= B * B) return;
    int i = idx >> 6, j = idx & 63;
    out[idx] = gram[idx] / sqrtf(gram[i * B + i] * gram[j * B + j]);
}

extern "C" void kernel_launch(void* const* d_in, const int* in_sizes, int n_in,
                              void* d_out, int out_size, void* d_ws, size_t ws_size,
                              hipStream_t stream) {
    const int*   esrc = (const int*)d_in[0];
    const int*   edst = (const int*)d_in[1];
    const int*   lab0 = (const int*)d_in[2];
    const float* hw   = (const float*)d_in[3];

    char* ws = (char*)d_ws;
    int*          Kmax  = (int*)(ws + K_OFF);
    unsigned int* feats = (unsigned int*)(ws + FEATS_OFF);
    unsigned int* adj   = (unsigned int*)(ws + ADJ_OFF);
    unsigned int* keys  = (unsigned int*)(ws + KEYS_OFF);
    int*          cnt   = (int*)(ws + CNT_OFF);
    float*        gram  = (float*)(ws + GRAM_OFF);

    hipMemsetAsync(d_ws, 0, ZERO_BYTES, stream);      // Kmax + feats

    build_adj_k<<<(B * E + 255) / 256, 256, 0, stream>>>(esrc, edst, adj);
    kmax_k<<<B * N / 256, 256, 0, stream>>>(adj, Kmax);
    init_hash_k<<<B, 1024, 0, stream>>>(adj, Kmax, hw, lab0, feats, keys);

    for (int it = 0; it < NITER; ++it) {
        count_k<<<B * 4, 256, 0, stream>>>(keys, cnt);
        rankhash_k<<<B, 1024, 0, stream>>>(adj, Kmax, hw, cnt, feats, keys,
                                           it < NITER - 1 ? 1 : 0);
    }

    gram_k<<<dim3(B, B), 64, 0, stream>>>(feats, gram);
    norm_k<<<(B * B + 255) / 256, 256, 0, stream>>>(gram, (float*)d_out);
}

// Round 5
// 261.490 us; speedup vs baseline: 1.2974x; 1.2974x over previous
//
#include <hip/hip_runtime.h>

#define B 64
#define N 1024
#define E 16384
#define WPR 32          // words per adjacency row = N/32
#define NITER 5

// ---- workspace layout (bytes) ----
// [ Kmax 256B | feats 256KiB ] <- zeroed by memset each call
// [ adj 8MiB | lab 256KiB | gram 16KiB ] <- fully overwritten each call
// NOTE: harness poisons d_ws with 0xAA. adj is safe ONLY because build_adj_k
// STORES every row (no read-modify-write on global). R4's bug: atomicOr onto
// unzeroed adj -> 0xAA garbage bits (deg~512) -> 30x hash work + wrong graph.
#define K_OFF     0
#define FEATS_OFF 256
#define FEATS_BYTES ((size_t)B * N * 4)
#define ZERO_BYTES (FEATS_OFF + FEATS_BYTES)
#define ADJ_OFF   ZERO_BYTES
#define ADJ_BYTES ((size_t)B * N * WPR * 4)
#define LAB_OFF   (ADJ_OFF + ADJ_BYTES)
#define LAB_BYTES ((size_t)B * N * 4)
#define GRAM_OFF  (LAB_OFF + LAB_BYTES)

// Bit adjacency built in LDS, full rows STORED to global (clean 64B lines;
// R2's global-atomicOr build was HBM partial-line-RMW bound: 33MB writes, 42us).
// 2 blocks/graph x 1024 threads (16 waves hide edge-read latency; R3's slow
// variant had only 4 waves and 4x edge re-read). Fused per-graph max-degree.
__global__ void __launch_bounds__(1024) build_adj_k(const int* __restrict__ src,
                                                    const int* __restrict__ dst,
                                                    unsigned int* __restrict__ adj,
                                                    int* __restrict__ Kmax) {
    __shared__ unsigned int s_adj[512 * WPR];       // 64 KiB: 512 rows
    int t = threadIdx.x;
    int b = blockIdx.x >> 1;
    int half = blockIdx.x & 1;
    int row_base = half << 9;

    uint4* s4 = (uint4*)s_adj;
#pragma unroll
    for (int k = 0; k < 4; ++k) s4[t + k * 1024] = make_uint4(0, 0, 0, 0);
    __syncthreads();

    const int* sg = src + (size_t)b * E;
    const int* dg = dst + (size_t)b * E;
#pragma unroll
    for (int k = 0; k < 16; ++k) {
        int e = t + k * 1024;
        int s = sg[e];
        int d = dg[e];
        int r = s - row_base;
        if ((unsigned)r < 512u)
            atomicOr(&s_adj[r * WPR + (d >> 5)], 1u << (d & 31));  // idempotent dedup
    }
    __syncthreads();

    // coalesced full-row writeout (LDS layout == global layout for these rows)
    uint4* g4 = (uint4*)(adj + ((size_t)b * N + row_base) * WPR);
#pragma unroll
    for (int k = 0; k < 4; ++k) g4[t + k * 1024] = s4[t + k * 1024];

    // fused Kmax: threads 0..511 popcount their row, wave shfl-max, LDS combine
    int dmax = 0;
    if (t < 512) {
        const uint4* row = (const uint4*)(s_adj + t * WPR);
        int dd = 0;
#pragma unroll
        for (int w = 0; w < 8; ++w) {
            uint4 v = row[w];
            dd += __popc(v.x) + __popc(v.y) + __popc(v.z) + __popc(v.w);
        }
        dmax = dd;
    }
#pragma unroll
    for (int off = 32; off > 0; off >>= 1) dmax = max(dmax, __shfl_down(dmax, off));
    __syncthreads();                                // all row reads done
    if ((t & 63) == 0) s_adj[t >> 6] = (unsigned)dmax;
    __syncthreads();
    if (t == 0) {
        int m = 0;
#pragma unroll
        for (int k = 0; k < 16; ++k) m = max(m, (int)s_adj[k]);
        atomicMax(&Kmax[b], m);
    }
}

// deg/seg from bit row + exact-_rn hash (bitwise == numpy) -> monotone uint key
__device__ __forceinline__ unsigned int hash_key(const unsigned int* __restrict__ row,
                                                 const int* s_lab, int my_lab,
                                                 float Kf, float w0, float w1) {
    int s = 0, d = 0;
#pragma unroll 4
    for (int w = 0; w < WPR; ++w) {
        unsigned int word = row[w];
        d += __popc(word);
        int base = w << 5;
        while (word) {
            int j = __ffs(word) - 1;
            word &= word - 1;
            s += s_lab[base + j];
        }
    }
    float t1 = __fmul_rn(__fmul_rn(Kf, w0), (float)my_lab);
    float t2 = __fmul_rn(w1, __fsub_rn(__fadd_rn((float)s, (float)d), Kf));
    float h  = __fadd_rn(t1, t2);
    unsigned int bits = __float_as_uint(h);
    if (bits == 0x80000000u) bits = 0u;             // -0 == +0
    return (bits & 0x80000000u) ? ~bits : (bits | 0x80000000u);
}

// One fused WL iteration per graph per block:
//   (iter 0: bincount initial labels <16)
//   hash -> keys; count c_i = #{j: key_j < key_i} with 256 threads x 4 keys
//   (1024 b128 LDS broadcasts/block, 4x less than R3's one-key-per-thread);
//   class-start flags + shfl scan -> dense rank; scatter labels; bincount.
__global__ void __launch_bounds__(1024) wl_iter_k(const unsigned int* __restrict__ adj,
                                                  const int* __restrict__ Kmax,
                                                  const float* __restrict__ hw,
                                                  const int* __restrict__ lab0,
                                                  int* __restrict__ lab,
                                                  unsigned int* __restrict__ feats,
                                                  int iter) {
    __shared__ int s_lab[N];
    __shared__ unsigned int s_key[N];
    __shared__ int s_cnt[N];            // counts, then reused for scan values
    __shared__ int s_a[N];              // flags, then reused for rank bincount
    __shared__ int s_wsum[16];          // wave sums; also iter0 label bincount
    int b = blockIdx.x, t = threadIdx.x;
    int lane = t & 63, w = t >> 6;

    int l = (iter == 0) ? lab0[(size_t)b * N + t] : lab[(size_t)b * N + t];
    s_lab[t] = l;
    if (iter == 0 && t < 16) s_wsum[t] = 0;
    __syncthreads();
    if (iter == 0) atomicAdd(&s_wsum[l], 1);

    unsigned int ikey = hash_key(adj + ((size_t)b * N + t) * WPR, s_lab, l,
                                 (float)Kmax[b], hw[0], hw[1]);
    s_key[t] = ikey;
    s_a[t] = 0;
    __syncthreads();
    if (iter == 0 && t < 16) feats[(size_t)b * N + t] = (unsigned)s_wsum[t];

    if (t < 256) {
        unsigned int k0 = s_key[t], k1 = s_key[t + 256],
                     k2 = s_key[t + 512], k3 = s_key[t + 768];
        int c0 = 0, c1 = 0, c2 = 0, c3 = 0;
        const uint4* k4 = (const uint4*)s_key;
#pragma unroll 4
        for (int j = 0; j < N / 4; ++j) {
            uint4 v = k4[j];
            c0 += (v.x < k0) + (v.y < k0) + (v.z < k0) + (v.w < k0);
            c1 += (v.x < k1) + (v.y < k1) + (v.z < k1) + (v.w < k1);
            c2 += (v.x < k2) + (v.y < k2) + (v.z < k2) + (v.w < k2);
            c3 += (v.x < k3) + (v.y < k3) + (v.z < k3) + (v.w < k3);
        }
        s_cnt[t] = c0; s_cnt[t + 256] = c1; s_cnt[t + 512] = c2; s_cnt[t + 768] = c3;
    }
    __syncthreads();
    int c = s_cnt[t];
    s_a[c] = 1;                         // same class -> same c (benign race)
    __syncthreads();

    // inclusive scan of flags: shfl intra-wave + serial wave prefix
    int f = s_a[t];
#pragma unroll
    for (int d = 1; d < 64; d <<= 1) {
        int v = __shfl_up(f, d);
        if (lane >= d) f += v;
    }
    if (lane == 63) s_wsum[w] = f;
    __syncthreads();
    if (t == 0) {
        int run = 0;
#pragma unroll
        for (int k = 0; k < 16; ++k) { int tmp = s_wsum[k]; s_wsum[k] = run; run += tmp; }
    }
    __syncthreads();
    s_cnt[t] = f + s_wsum[w];           // c already in registers everywhere
    __syncthreads();
    int rank = s_cnt[c] - 1;
    lab[(size_t)b * N + t] = rank;

    s_a[t] = 0;
    __syncthreads();
    atomicAdd(&s_a[rank], 1);
    __syncthreads();
    int add = s_a[t];
    if (add) feats[(size_t)b * N + t] += (unsigned)add;
}

// gram[i,j] = dot(feats[i], feats[j]) — exact in int32
__global__ void gram_k(const unsigned int* __restrict__ feats, float* __restrict__ gram) {
    int i = blockIdx.x, j = blockIdx.y;
    int lane = threadIdx.x;
    const unsigned int* fi = feats + (size_t)i * N;
    const unsigned int* fj = feats + (size_t)j * N;
    int s = 0;
    for (int l = lane; l < N; l += 64) s += (int)(fi[l] * fj[l]);
#pragma unroll
    for (int off = 32; off > 0; off >>= 1) s += __shfl_down(s, off);
    if (lane == 0) gram[i * B + j] = (float)s;
}

__global__ void norm_k(const float* __restrict__ gram, float* __restrict__ out) {
    int idx = blockIdx.x * blockDim.x + threadIdx.x;
    if (idx >= B * B) return;
    int i = idx >> 6, j = idx & 63;
    out[idx] = gram[idx] / sqrtf(gram[i * B + i] * gram[j * B + j]);
}

extern "C" void kernel_launch(void* const* d_in, const int* in_sizes, int n_in,
                              void* d_out, int out_size, void* d_ws, size_t ws_size,
                              hipStream_t stream) {
    const int*   esrc = (const int*)d_in[0];
    const int*   edst = (const int*)d_in[1];
    const int*   lab0 = (const int*)d_in[2];
    const float* hw   = (const float*)d_in[3];

    char* ws = (char*)d_ws;
    int*          Kmax  = (int*)(ws + K_OFF);
    unsigned int* feats = (unsigned int*)(ws + FEATS_OFF);
    unsigned int* adj   = (unsigned int*)(ws + ADJ_OFF);
    int*          lab   = (int*)(ws + LAB_OFF);
    float*        gram  = (float*)(ws + GRAM_OFF);

    hipMemsetAsync(d_ws, 0, ZERO_BYTES, stream);    // Kmax + feats only

    build_adj_k<<<B * 2, 1024, 0, stream>>>(esrc, edst, adj, Kmax);

    for (int it = 0; it < NITER; ++it)
        wl_iter_k<<<B, 1024, 0, stream>>>(adj, Kmax, hw, lab0, lab, feats, it);

    gram_k<<<dim3(B, B), 64, 0, stream>>>(feats, gram);
    norm_k<<<(B * B + 255) / 256, 256, 0, stream>>>(gram, (float*)d_out);
}

// Round 6
// 166.161 us; speedup vs baseline: 2.0418x; 1.5737x over previous
//
#include <hip/hip_runtime.h>

#define B 64
#define N 1024
#define E 16384
#define WPR 32          // words per adjacency row = N/32
#define NITER 5

// ---- workspace layout (bytes) ----
// [ Kmax 256B | feats 256KiB ] <- zeroed by memset each call
// [ adj 8MiB | lab 256KiB | keys 256KiB | gram 16KiB ] <- fully overwritten
// harness poisons d_ws with 0xAA: adj is safe only because build STORES every
// row (no global RMW). Keys/lab fully written before read each iteration.
#define K_OFF     0
#define FEATS_OFF 256
#define FEATS_BYTES ((size_t)B * N * 4)
#define ZERO_BYTES (FEATS_OFF + FEATS_BYTES)
#define ADJ_OFF   ZERO_BYTES
#define ADJ_BYTES ((size_t)B * N * WPR * 4)
#define LAB_OFF   (ADJ_OFF + ADJ_BYTES)
#define KEYS_OFF  (LAB_OFF + (size_t)B * N * 4)
#define GRAM_OFF  (KEYS_OFF + (size_t)B * N * 4)

// Bit adjacency built in LDS, full rows STORED to global (R5-measured good).
__global__ void __launch_bounds__(1024) build_adj_k(const int* __restrict__ src,
                                                    const int* __restrict__ dst,
                                                    unsigned int* __restrict__ adj,
                                                    int* __restrict__ Kmax) {
    __shared__ unsigned int s_adj[512 * WPR];       // 64 KiB: 512 rows
    int t = threadIdx.x;
    int b = blockIdx.x >> 1;
    int half = blockIdx.x & 1;
    int row_base = half << 9;

    uint4* s4 = (uint4*)s_adj;
#pragma unroll
    for (int k = 0; k < 4; ++k) s4[t + k * 1024] = make_uint4(0, 0, 0, 0);
    __syncthreads();

    const int* sg = src + (size_t)b * E;
    const int* dg = dst + (size_t)b * E;
#pragma unroll
    for (int k = 0; k < 16; ++k) {
        int e = t + k * 1024;
        int s = sg[e];
        int d = dg[e];
        int r = s - row_base;
        if ((unsigned)r < 512u)
            atomicOr(&s_adj[r * WPR + (d >> 5)], 1u << (d & 31));  // idempotent dedup
    }
    __syncthreads();

    uint4* g4 = (uint4*)(adj + ((size_t)b * N + row_base) * WPR);
#pragma unroll
    for (int k = 0; k < 4; ++k) g4[t + k * 1024] = s4[t + k * 1024];

    int dmax = 0;
    if (t < 512) {
        const uint4* row = (const uint4*)(s_adj + t * WPR);
        int dd = 0;
#pragma unroll
        for (int w = 0; w < 8; ++w) {
            uint4 v = row[w];
            dd += __popc(v.x) + __popc(v.y) + __popc(v.z) + __popc(v.w);
        }
        dmax = dd;
    }
#pragma unroll
    for (int off = 32; off > 0; off >>= 1) dmax = max(dmax, __shfl_down(dmax, off));
    __syncthreads();
    if ((t & 63) == 0) s_adj[t >> 6] = (unsigned)dmax;
    __syncthreads();
    if (t == 0) {
        int m = 0;
#pragma unroll
        for (int k = 0; k < 16; ++k) m = max(m, (int)s_adj[k]);
        atomicMax(&Kmax[b], m);
    }
}

// initial feats = bincount of lab0 (<16). One block per graph.
__global__ void __launch_bounds__(1024) init_feats_k(const int* __restrict__ lab0,
                                                     unsigned int* __restrict__ feats) {
    __shared__ unsigned int cnt[16];
    int b = blockIdx.x, t = threadIdx.x;
    if (t < 16) cnt[t] = 0;
    __syncthreads();
    atomicAdd(&cnt[lab0[(size_t)b * N + t]], 1u);
    __syncthreads();
    if (t < 16) feats[(size_t)b * N + t] = cnt[t];   // feats pre-zeroed
}

// hash: 4 blocks/graph (256 blocks -> all CUs), 256 threads, 1 node/thread.
// deg/seg from bit row (ffs-walk, labels in LDS) + exact-_rn hash order
// -> bitwise-identical float h vs numpy. Writes keys (float).
__global__ void __launch_bounds__(256) hash_k(const unsigned int* __restrict__ adj,
                                              const int* __restrict__ Kmax,
                                              const float* __restrict__ hw,
                                              const int* __restrict__ lab_src,
                                              float* __restrict__ keys) {
    __shared__ int s_lab[N];
    int t = threadIdx.x;
    int b = blockIdx.x >> 2;
    int node = ((blockIdx.x & 3) << 8) + t;
    ((int4*)s_lab)[t] = ((const int4*)(lab_src + (size_t)b * N))[t];
    __syncthreads();

    const unsigned int* row = adj + ((size_t)b * N + node) * WPR;
    int s = 0, d = 0;
#pragma unroll 4
    for (int w = 0; w < WPR; ++w) {
        unsigned int word = row[w];
        d += __popc(word);
        int base = w << 5;
        while (word) {
            int j = __ffs(word) - 1;
            word &= word - 1;
            s += s_lab[base + j];
        }
    }
    float t1 = __fmul_rn(__fmul_rn((float)Kmax[b], hw[0]), (float)s_lab[node]);
    float t2 = __fmul_rn(hw[1], __fsub_rn(__fadd_rn((float)s, (float)d), (float)Kmax[b]));
    keys[(size_t)b * N + node] = __fadd_rn(t1, t2);
}

// dense rank (unique-inverse) via monotone value-linear bucketization:
//   block min/max -> bucket = (h-min)*1023/(max-min)  (order-preserving),
//   LDS hist + scan -> grouped scatter; c_i = bucket_start + within-bucket
//   strict-less (expected segment ~1-3 for spread hashes; degenerate all-equal
//   case degrades to O(N) loop but stays correct);
//   class-start flags + scan -> rank; bincount ranks into feats.
// One block per graph, all 16 waves busy (R5's O(N^2) count ran on 4 waves).
__global__ void __launch_bounds__(1024) rank_k(const float* __restrict__ keys,
                                               int* __restrict__ lab,
                                               unsigned int* __restrict__ feats) {
    __shared__ float s_grp[N];
    __shared__ int s_hist[N];
    __shared__ int s_scan[N];
    __shared__ int s_wsum[16];
    __shared__ float s_mn[17], s_mx[17];
    int b = blockIdx.x, t = threadIdx.x;
    int lane = t & 63, w = t >> 6;

    float h = keys[(size_t)b * N + t];

    // block min/max of h
    float mn = h, mx = h;
#pragma unroll
    for (int off = 32; off > 0; off >>= 1) {
        mn = fminf(mn, __shfl_down(mn, off));
        mx = fmaxf(mx, __shfl_down(mx, off));
    }
    if (lane == 0) { s_mn[w] = mn; s_mx[w] = mx; }
    s_hist[t] = 0;
    __syncthreads();
    if (t == 0) {
        float a = s_mn[0], c = s_mx[0];
#pragma unroll
        for (int k = 1; k < 16; ++k) { a = fminf(a, s_mn[k]); c = fmaxf(c, s_mx[k]); }
        s_mn[16] = a; s_mx[16] = c;
    }
    __syncthreads();
    float fmn = s_mn[16];
    float span = s_mx[16] - fmn;
    float scale = (span > 0.f) ? (1023.0f / span) : 0.f;
    int bucket = min((int)((h - fmn) * scale), 1023);

    int off_in = atomicAdd(&s_hist[bucket], 1);
    __syncthreads();

    // inclusive scan of bucket sizes
    int f = s_hist[t];
#pragma unroll
    for (int d = 1; d < 64; d <<= 1) {
        int v = __shfl_up(f, d);
        if (lane >= d) f += v;
    }
    if (lane == 63) s_wsum[w] = f;
    __syncthreads();
    if (t == 0) {
        int run = 0;
#pragma unroll
        for (int k = 0; k < 16; ++k) { int tmp = s_wsum[k]; s_wsum[k] = run; run += tmp; }
    }
    __syncthreads();
    s_scan[t] = f + s_wsum[w];
    __syncthreads();

    int start = s_scan[bucket] - s_hist[bucket];
    int end   = s_scan[bucket];
    s_grp[start + off_in] = h;
    __syncthreads();

    int c = start;                       // all lower-bucket keys are strictly less
    for (int k = start; k < end; ++k) c += (s_grp[k] < h);
    __syncthreads();                     // all reads of s_hist/s_grp done

    // class-start flags + scan -> dense rank
    s_hist[t] = 0;
    __syncthreads();
    s_hist[c] = 1;                       // same class -> same c (benign race)
    __syncthreads();
    f = s_hist[t];
#pragma unroll
    for (int d = 1; d < 64; d <<= 1) {
        int v = __shfl_up(f, d);
        if (lane >= d) f += v;
    }
    if (lane == 63) s_wsum[w] = f;
    __syncthreads();
    if (t == 0) {
        int run = 0;
#pragma unroll
        for (int k = 0; k < 16; ++k) { int tmp = s_wsum[k]; s_wsum[k] = run; run += tmp; }
    }
    __syncthreads();
    s_scan[t] = f + s_wsum[w];
    __syncthreads();
    int rank = s_scan[c] - 1;
    lab[(size_t)b * N + t] = rank;

    // bincount ranks -> feats (row b owned by this block)
    s_hist[t] = 0;
    __syncthreads();
    atomicAdd(&s_hist[rank], 1);
    __syncthreads();
    int add = s_hist[t];
    if (add) feats[(size_t)b * N + t] += (unsigned)add;
}

// gram[i,j] = dot(feats[i], feats[j]) — exact in int32
__global__ void gram_k(const unsigned int* __restrict__ feats, float* __restrict__ gram) {
    int i = blockIdx.x, j = blockIdx.y;
    int lane = threadIdx.x;
    const unsigned int* fi = feats + (size_t)i * N;
    const unsigned int* fj = feats + (size_t)j * N;
    int s = 0;
    for (int l = lane; l < N; l += 64) s += (int)(fi[l] * fj[l]);
#pragma unroll
    for (int off = 32; off > 0; off >>= 1) s += __shfl_down(s, off);
    if (lane == 0) gram[i * B + j] = (float)s;
}

__global__ void norm_k(const float* __restrict__ gram, float* __restrict__ out) {
    int idx = blockIdx.x * blockDim.x + threadIdx.x;
    if (idx >= B * B) return;
    int i = idx >> 6, j = idx & 63;
    out[idx] = gram[idx] / sqrtf(gram[i * B + i] * gram[j * B + j]);
}

extern "C" void kernel_launch(void* const* d_in, const int* in_sizes, int n_in,
                              void* d_out, int out_size, void* d_ws, size_t ws_size,
                              hipStream_t stream) {
    const int*   esrc = (const int*)d_in[0];
    const int*   edst = (const int*)d_in[1];
    const int*   lab0 = (const int*)d_in[2];
    const float* hw   = (const float*)d_in[3];

    char* ws = (char*)d_ws;
    int*          Kmax  = (int*)(ws + K_OFF);
    unsigned int* feats = (unsigned int*)(ws + FEATS_OFF);
    unsigned int* adj   = (unsigned int*)(ws + ADJ_OFF);
    int*          lab   = (int*)(ws + LAB_OFF);
    float*        keys  = (float*)(ws + KEYS_OFF);
    float*        gram  = (float*)(ws + GRAM_OFF);

    hipMemsetAsync(d_ws, 0, ZERO_BYTES, stream);    // Kmax + feats only

    build_adj_k<<<B * 2, 1024, 0, stream>>>(esrc, edst, adj, Kmax);
    init_feats_k<<<B, 1024, 0, stream>>>(lab0, feats);

    for (int it = 0; it < NITER; ++it) {
        hash_k<<<B * 4, 256, 0, stream>>>(adj, Kmax, hw, it == 0 ? lab0 : lab, keys);
        rank_k<<<B, 1024, 0, stream>>>(keys, lab, feats);
    }

    gram_k<<<dim3(B, B), 64, 0, stream>>>(feats, gram);
    norm_k<<<(B * B + 255) / 256, 256, 0, stream>>>(gram, (float*)d_out);
}

// Round 7
// 121.727 us; speedup vs baseline: 2.7871x; 1.3650x over previous
//
#include <hip/hip_runtime.h>

#define B 64
#define N 1024
#define E 16384
#define WPR 32          // words per adjacency row = N/32
#define NITER 5

// ---- workspace layout (bytes) ---- (NO memset needed: every region is
// fully stored before any read; harness 0xAA poison is harmless)
#define ADJ_OFF   0
#define ADJ_BYTES ((size_t)B * N * WPR * 4)
#define FEATS_OFF ADJ_BYTES
#define GRAM_OFF  (FEATS_OFF + (size_t)B * N * 4)

// Bit adjacency built in LDS, full rows STORED to global (R5/R6-measured ~9us;
// stores-only => safe against workspace poison). Kmax removed (mega computes K).
__global__ void __launch_bounds__(1024) build_adj_k(const int* __restrict__ src,
                                                    const int* __restrict__ dst,
                                                    unsigned int* __restrict__ adj) {
    __shared__ unsigned int s_adj[512 * WPR];       // 64 KiB: 512 rows
    int t = threadIdx.x;
    int b = blockIdx.x >> 1;
    int half = blockIdx.x & 1;
    int row_base = half << 9;

    uint4* s4 = (uint4*)s_adj;
#pragma unroll
    for (int k = 0; k < 4; ++k) s4[t + k * 1024] = make_uint4(0, 0, 0, 0);
    __syncthreads();

    const int* sg = src + (size_t)b * E;
    const int* dg = dst + (size_t)b * E;
#pragma unroll
    for (int k = 0; k < 16; ++k) {
        int e = t + k * 1024;
        int s = sg[e];
        int d = dg[e];
        int r = s - row_base;
        if ((unsigned)r < 512u)
            atomicOr(&s_adj[r * WPR + (d >> 5)], 1u << (d & 31));  // idempotent dedup
    }
    __syncthreads();

    uint4* g4 = (uint4*)(adj + ((size_t)b * N + row_base) * WPR);
#pragma unroll
    for (int k = 0; k < 4; ++k) g4[t + k * 1024] = s4[t + k * 1024];
}

// Whole WL loop, one block per graph, fully LDS-resident:
//   Phase A: read own bitmask row (32 regs), deg=popcount, scan->CSR offsets,
//            walk bits ONCE -> compact u16 neighbor list (<=E entries = 32KB),
//            K = max deg (in-block reduce), init label bincount.
//   Phase B (x5): seg_i = sum s_lab[nbr] (<=~40 independent LDS gathers),
//            exact-_rn hash (bitwise == numpy), bucketized dense rank
//            (R6-verified: order-preserving linear buckets + within-bucket
//            strict-less + class-start flags + scan), bincount into s_feats.
//   No global traffic inside the loop; kills 10 launches + 5x ffs re-walks.
__global__ void __launch_bounds__(1024) wl_mega_k(const unsigned int* __restrict__ adj,
                                                  const int* __restrict__ lab0,
                                                  const float* __restrict__ hw,
                                                  unsigned int* __restrict__ feats) {
    __shared__ unsigned short s_nbr[E];   // 32 KB compact CSR payload
    __shared__ int s_lab[N];
    __shared__ int s_hist[N];
    __shared__ int s_scan[N];
    __shared__ float s_grp[N];
    __shared__ unsigned int s_feats[N];
    __shared__ int s_wsum[16];
    __shared__ float s_mn[17], s_mx[17];
    __shared__ int s_K;
    int b = blockIdx.x, t = threadIdx.x;
    int lane = t & 63, w = t >> 6;

    // ---- Phase A ----
    uint4 r[8];
    const uint4* rowg = (const uint4*)(adj + ((size_t)b * N + t) * WPR);
#pragma unroll
    for (int k = 0; k < 8; ++k) r[k] = rowg[k];
    int dg = 0;
#pragma unroll
    for (int k = 0; k < 8; ++k)
        dg += __popc(r[k].x) + __popc(r[k].y) + __popc(r[k].z) + __popc(r[k].w);

    // inclusive scan of deg -> exclusive CSR offset
    int f = dg;
#pragma unroll
    for (int d2 = 1; d2 < 64; d2 <<= 1) {
        int v = __shfl_up(f, d2);
        if (lane >= d2) f += v;
    }
    if (lane == 63) s_wsum[w] = f;
    // K = max deg (reuse s_scan as scratch)
    int km = dg;
#pragma unroll
    for (int off6 = 32; off6 > 0; off6 >>= 1) km = max(km, __shfl_down(km, off6));
    if (lane == 0) s_scan[w] = km;
    __syncthreads();
    if (t == 0) {
        int run = 0, m = 0;
#pragma unroll
        for (int k = 0; k < 16; ++k) {
            int tmp = s_wsum[k]; s_wsum[k] = run; run += tmp;
            m = max(m, s_scan[k]);
        }
        s_K = m;
    }
    __syncthreads();
    int off = f + s_wsum[w] - dg;       // this node's CSR start

    // pack own row's set bits -> u16 neighbor ids
    {
        int idx = off;
#pragma unroll
        for (int k = 0; k < 8; ++k) {
            unsigned int wv[4] = { r[k].x, r[k].y, r[k].z, r[k].w };
#pragma unroll
            for (int c2 = 0; c2 < 4; ++c2) {
                unsigned int word = wv[c2];
                int base = (k * 4 + c2) << 5;
                while (word) {
                    int j = __ffs(word) - 1;
                    word &= word - 1;
                    s_nbr[idx++] = (unsigned short)(base + j);
                }
            }
        }
    }
    // labels + init bincount (labels < 16)
    int l0 = lab0[(size_t)b * N + t];
    s_lab[t] = l0;
    s_feats[t] = 0;
    __syncthreads();
    atomicAdd(&s_feats[l0], 1u);

    float w0 = hw[0], w1 = hw[1];
    float Kf = (float)s_K;
    __syncthreads();

    // ---- Phase B: 5 WL iterations ----
    for (int it = 0; it < NITER; ++it) {
        // hash (exact _rn op order -> bitwise == numpy)
        int s = 0;
        for (int k = 0; k < dg; ++k) s += s_lab[s_nbr[off + k]];
        float t1 = __fmul_rn(__fmul_rn(Kf, w0), (float)s_lab[t]);
        float t2 = __fmul_rn(w1, __fsub_rn(__fadd_rn((float)s, (float)dg), Kf));
        float h  = __fadd_rn(t1, t2);

        // block min/max
        float mn = h, mx = h;
#pragma unroll
        for (int o = 32; o > 0; o >>= 1) {
            mn = fminf(mn, __shfl_down(mn, o));
            mx = fmaxf(mx, __shfl_down(mx, o));
        }
        if (lane == 0) { s_mn[w] = mn; s_mx[w] = mx; }
        s_hist[t] = 0;
        __syncthreads();
        if (t == 0) {
            float a = s_mn[0], c = s_mx[0];
#pragma unroll
            for (int k = 1; k < 16; ++k) { a = fminf(a, s_mn[k]); c = fmaxf(c, s_mx[k]); }
            s_mn[16] = a; s_mx[16] = c;
        }
        __syncthreads();
        float fmn = s_mn[16];
        float span = s_mx[16] - fmn;
        float scale = (span > 0.f) ? (1023.0f / span) : 0.f;
        int bucket = min((int)((h - fmn) * scale), 1023);
        int off_in = atomicAdd(&s_hist[bucket], 1);
        __syncthreads();

        // inclusive scan of bucket sizes
        f = s_hist[t];
#pragma unroll
        for (int d2 = 1; d2 < 64; d2 <<= 1) {
            int v = __shfl_up(f, d2);
            if (lane >= d2) f += v;
        }
        if (lane == 63) s_wsum[w] = f;
        __syncthreads();
        if (t == 0) {
            int run = 0;
#pragma unroll
            for (int k = 0; k < 16; ++k) { int tmp = s_wsum[k]; s_wsum[k] = run; run += tmp; }
        }
        __syncthreads();
        s_scan[t] = f + s_wsum[w];
        __syncthreads();

        int start = s_scan[bucket] - s_hist[bucket];
        int end   = s_scan[bucket];
        s_grp[start + off_in] = h;
        __syncthreads();
        int c = start;                   // lower buckets are strictly less (monotone)
        for (int k = start; k < end; ++k) c += (s_grp[k] < h);
        __syncthreads();

        // class-start flags + scan -> dense rank
        s_hist[t] = 0;
        __syncthreads();
        s_hist[c] = 1;                   // same class -> same c (benign race)
        __syncthreads();
        f = s_hist[t];
#pragma unroll
        for (int d2 = 1; d2 < 64; d2 <<= 1) {
            int v = __shfl_up(f, d2);
            if (lane >= d2) f += v;
        }
        if (lane == 63) s_wsum[w] = f;
        __syncthreads();
        if (t == 0) {
            int run = 0;
#pragma unroll
            for (int k = 0; k < 16; ++k) { int tmp = s_wsum[k]; s_wsum[k] = run; run += tmp; }
        }
        __syncthreads();
        s_scan[t] = f + s_wsum[w];
        __syncthreads();
        int rank = s_scan[c] - 1;
        s_lab[t] = rank;
        atomicAdd(&s_feats[rank], 1u);
        __syncthreads();                 // protects s_lab/s_hist/s_scan reuse
    }

    feats[(size_t)b * N + t] = s_feats[t];
}

// gram[i,j] = dot(feats[i], feats[j]) — exact in int32 (max ~6.3e6 < 2^24)
__global__ void gram_k(const unsigned int* __restrict__ feats, float* __restrict__ gram) {
    int i = blockIdx.x, j = blockIdx.y;
    int lane = threadIdx.x;
    const unsigned int* fi = feats + (size_t)i * N;
    const unsigned int* fj = feats + (size_t)j * N;
    int s = 0;
    for (int l = lane; l < N; l += 64) s += (int)(fi[l] * fj[l]);
#pragma unroll
    for (int off = 32; off > 0; off >>= 1) s += __shfl_down(s, off);
    if (lane == 0) gram[i * B + j] = (float)s;
}

__global__ void norm_k(const float* __restrict__ gram, float* __restrict__ out) {
    int idx = blockIdx.x * blockDim.x + threadIdx.x;
    if (idx >= B * B) return;
    int i = idx >> 6, j = idx & 63;
    out[idx] = gram[idx] / sqrtf(gram[i * B + i] * gram[j * B + j]);
}

extern "C" void kernel_launch(void* const* d_in, const int* in_sizes, int n_in,
                              void* d_out, int out_size, void* d_ws, size_t ws_size,
                              hipStream_t stream) {
    const int*   esrc = (const int*)d_in[0];
    const int*   edst = (const int*)d_in[1];
    const int*   lab0 = (const int*)d_in[2];
    const float* hw   = (const float*)d_in[3];

    char* ws = (char*)d_ws;
    unsigned int* adj   = (unsigned int*)(ws + ADJ_OFF);
    unsigned int* feats = (unsigned int*)(ws + FEATS_OFF);
    float*        gram  = (float*)(ws + GRAM_OFF);

    build_adj_k<<<B * 2, 1024, 0, stream>>>(esrc, edst, adj);
    wl_mega_k<<<B, 1024, 0, stream>>>(adj, lab0, hw, feats);
    gram_k<<<dim3(B, B), 64, 0, stream>>>(feats, gram);
    norm_k<<<(B * B + 255) / 256, 256, 0, stream>>>(gram, (float*)d_out);
}